// Round 3
// baseline (838.387 us; speedup 1.0000x reference)
//
#include <hip/hip_runtime.h>

#define NN 10000
#define MP 10112      // 79*128, padded row count for MFMA GEMM A-tiles
#define EE 100000
#define ETOT 110000   // EE + NN self loops
#define INC 256
#define HH 6
#define CC 128
#define FF 768        // HH*CC
#define BB 64
#define BN_EPS 1e-5f

typedef unsigned short ushort_t;
typedef unsigned int uint_t;
typedef __attribute__((ext_vector_type(8))) short bf16x8;
typedef __attribute__((ext_vector_type(4))) float f32x4;
#define AS1 __attribute__((address_space(1)))
#define AS3 __attribute__((address_space(3)))

// ---------- float <-> order-preserving uint encoding (for atomicMax on float) ----------
__device__ __forceinline__ unsigned fenc(float v){
  unsigned u = __float_as_uint(v);
  return (u & 0x80000000u) ? ~u : (u | 0x80000000u);
}
__device__ __forceinline__ float fdec(unsigned u){
  return (u & 0x80000000u) ? __uint_as_float(u & 0x7FFFFFFFu) : __uint_as_float(~u);
}
#define FENC_NEG_INF 0x007FFFFFu   // fenc(-inf)

__device__ __forceinline__ ushort_t f2bf(float v){   // RNE fp32 -> bf16
  unsigned u = __float_as_uint(v);
  u += 0x7FFFu + ((u >> 16) & 1u);
  return (ushort_t)(u >> 16);
}
__device__ __forceinline__ float bf_lo(uint_t u){ return __uint_as_float(u << 16); }
__device__ __forceinline__ float bf_hi(uint_t u){ return __uint_as_float(u & 0xFFFF0000u); }

// ---------- CSR build ----------
__global__ __launch_bounds__(256) void count_deg(const int* __restrict__ adj, int* __restrict__ deg){
  int k = blockIdx.x*256 + threadIdx.x;
  if(k >= ETOT) return;
  int d = (k < EE) ? adj[EE + k] : (k - EE);
  atomicAdd(deg + d, 1);
}

__global__ __launch_bounds__(1024) void scan_deg(const int* __restrict__ deg,
                                                 int* __restrict__ row_start,
                                                 int* __restrict__ pos){
  __shared__ int wsum[16];
  __shared__ int wexcl[16];
  __shared__ int carry, ctot;
  int t = threadIdx.x, wave = t >> 6, lane = t & 63;
  if(t == 0) carry = 0;
  __syncthreads();
  for(int base = 0; base < NN; base += 1024){
    int i = base + t;
    int v = (i < NN) ? deg[i] : 0;
    int s = v;
    #pragma unroll
    for(int off = 1; off < 64; off <<= 1){ int x = __shfl_up(s, off); if(lane >= off) s += x; }
    if(lane == 63) wsum[wave] = s;
    __syncthreads();
    if(t < 16){
      int ws = wsum[t], sc = ws;
      #pragma unroll
      for(int off = 1; off < 16; off <<= 1){ int x = __shfl_up(sc, off); if(t >= off) sc += x; }
      wexcl[t] = sc - ws;
      if(t == 15) ctot = sc;
    }
    __syncthreads();
    int c = carry;
    if(i < NN){ int excl = c + wexcl[wave] + s - v; row_start[i] = excl; pos[i] = excl; }
    __syncthreads();
    if(t == 0) carry = c + ctot;
  }
  __syncthreads();
  if(t == 0) row_start[NN] = carry;
}

__global__ __launch_bounds__(256) void scatter_edges(const int* __restrict__ adj,
                                                     int* __restrict__ pos,
                                                     int* __restrict__ csr_src,
                                                     int* __restrict__ csr_eid){
  int k = blockIdx.x*256 + threadIdx.x;
  if(k >= ETOT) return;
  int s, d;
  if(k < EE){ s = adj[k]; d = adj[EE + k]; } else { s = k - EE; d = s; }
  int i = atomicAdd(pos + d, 1);
  csr_src[i] = s;
  csr_eid[i] = k;
}

// ---------- fp32 -> bf16 convert ----------
__global__ __launch_bounds__(256) void conv_bf16(const float* __restrict__ in,
                                                 ushort_t* __restrict__ out, int n4){
  int i = blockIdx.x*256 + threadIdx.x;
  if(i >= n4) return;
  float4 v = ((const float4*)in)[i];
  ushort4 o;
  o.x = f2bf(v.x); o.y = f2bf(v.y); o.z = f2bf(v.z); o.w = f2bf(v.w);
  ((ushort4*)out)[i] = o;
}

// ---------- W[K,N] fp32 -> Wt[N,K] bf16, optional per-k scale (BN fold) ----------
__global__ __launch_bounds__(256) void transpose_bf(const float* __restrict__ in,
                                                    ushort_t* __restrict__ out,
                                                    int K, int N,
                                                    const float* __restrict__ sc){
  __shared__ ushort_t tile[32][33];
  int kb = blockIdx.y*32, nb = blockIdx.x*32;
  int tx = threadIdx.x & 31, ty = threadIdx.x >> 5;
  #pragma unroll
  for(int r = ty; r < 32; r += 8){
    float v = in[(size_t)(kb + r)*N + nb + tx];
    if(sc) v *= sc[kb + r];
    tile[tx][r] = f2bf(v);
  }
  __syncthreads();
  #pragma unroll
  for(int r = ty; r < 32; r += 8)
    out[(size_t)(nb + r)*K + kb + tx] = tile[r][tx];
}

// ---------- bias fold: out[o] = base[o] + sum_k shift[k]*W[k,o] ----------
__global__ __launch_bounds__(256) void bias_fold(const float* __restrict__ W,
                                                 const float* __restrict__ shift,
                                                 const float* __restrict__ base,
                                                 float* __restrict__ out, int K, int N){
  int o = blockIdx.x*256 + threadIdx.x;
  if(o >= N) return;
  float s = base ? base[o] : 0.f;
  for(int k = 0; k < K; k++) s = fmaf(shift[k], W[(size_t)k*N + o], s);
  out[o] = s;
}

// ---------- bf16 MFMA GEMM: C[M,N] = A[MP,K] * Bt[N,K]^T (+bias), out fp32 or bf16 ----------
__global__ __launch_bounds__(256) void gemm_bt(const ushort_t* __restrict__ A,
                                               const ushort_t* __restrict__ Bt,
                                               float* __restrict__ Cf,
                                               ushort_t* __restrict__ Cb,
                                               int M, int N, int K,
                                               const float* __restrict__ bias){
  __shared__ ushort_t As[128*32];
  __shared__ ushort_t Bs[128*32];
  int tid = threadIdx.x;
  int bm = blockIdx.y*128, bn = blockIdx.x*128;
  int w = tid >> 6, lane = tid & 63;
  int wr = (w >> 1)*64, wc = (w & 1)*64;
  int quad = lane >> 4, l15 = lane & 15;

  f32x4 acc[4][4];
  #pragma unroll
  for(int i=0;i<4;i++)
    #pragma unroll
    for(int j=0;j<4;j++) acc[i][j] = (f32x4){0.f,0.f,0.f,0.f};

  int ch0 = tid, ch1 = tid + 256;
  int ar0 = ch0 >> 2, ac0 = (ch0 & 3) << 3;
  int ar1 = ch1 >> 2, ac1 = (ch1 & 3) << 3;
  const ushort_t* Ag0 = A + (size_t)(bm + ar0)*K + ac0;
  const ushort_t* Ag1 = A + (size_t)(bm + ar1)*K + ac1;
  const ushort_t* Bg0 = Bt + (size_t)(bn + ar0)*K + ac0;
  const ushort_t* Bg1 = Bt + (size_t)(bn + ar1)*K + ac1;

  for(int k0 = 0; k0 < K; k0 += 32){
    __builtin_amdgcn_global_load_lds((const AS1 uint_t*)(Ag0 + k0),
                                     (AS3 uint_t*)(As + ch0*8), 16, 0, 0);
    __builtin_amdgcn_global_load_lds((const AS1 uint_t*)(Ag1 + k0),
                                     (AS3 uint_t*)(As + ch1*8), 16, 0, 0);
    __builtin_amdgcn_global_load_lds((const AS1 uint_t*)(Bg0 + k0),
                                     (AS3 uint_t*)(Bs + ch0*8), 16, 0, 0);
    __builtin_amdgcn_global_load_lds((const AS1 uint_t*)(Bg1 + k0),
                                     (AS3 uint_t*)(Bs + ch1*8), 16, 0, 0);
    __syncthreads();

    bf16x8 a[4], b[4];
    #pragma unroll
    for(int i=0;i<4;i++) a[i] = *(const bf16x8*)&As[(wr + i*16 + l15)*32 + quad*8];
    #pragma unroll
    for(int j=0;j<4;j++) b[j] = *(const bf16x8*)&Bs[(wc + j*16 + l15)*32 + quad*8];
    #pragma unroll
    for(int i=0;i<4;i++)
      #pragma unroll
      for(int j=0;j<4;j++)
        acc[i][j] = __builtin_amdgcn_mfma_f32_16x16x32_bf16(a[i], b[j], acc[i][j], 0, 0, 0);
    __syncthreads();
  }

  // epilogue: C/D layout col=lane&15, row=quad*4+reg
  #pragma unroll
  for(int j=0;j<4;j++){
    int gc = bn + wc + j*16 + l15;
    float bv = bias ? bias[gc] : 0.f;
    #pragma unroll
    for(int i=0;i<4;i++){
      #pragma unroll
      for(int r=0;r<4;r++){
        int gr = bm + wr + i*16 + quad*4 + r;
        if(gr < M){
          float val = acc[i][j][r] + bv;
          if(Cb) Cb[(size_t)gr*N + gc] = f2bf(val);
          else   Cf[(size_t)gr*N + gc] = val;
        }
      }
    }
  }
}

// ---------- per-node attention dots (bf16 hx): thread t owns channels 2t,2t+1; wave w = head ----------
__global__ __launch_bounds__(384) void att_dots(const ushort_t* __restrict__ hx,
                                                const float* __restrict__ atts,
                                                const float* __restrict__ attd,
                                                float* __restrict__ a_s,
                                                float* __restrict__ a_d){
  int n = blockIdx.x, t = threadIdx.x, wave = t >> 6, lane = t & 63;
  uint_t u = ((const uint_t*)(hx + (size_t)n*FF))[t];
  float lo = bf_lo(u), hi = bf_hi(u);
  float2 as = ((const float2*)atts)[t];
  float2 ad = ((const float2*)attd)[t];
  float s = lo*as.x + hi*as.y;
  float d = lo*ad.x + hi*ad.y;
  #pragma unroll
  for(int off = 1; off < 64; off <<= 1){ s += __shfl_xor(s, off); d += __shfl_xor(d, off); }
  if(lane == 0){ a_s[n*6 + wave] = s; a_d[n*6 + wave] = d; }
}

// ---------- edge softmax weights (no max-subtraction; logits are O(1) by construction) ----------
__global__ __launch_bounds__(256) void edge_soft(const int* __restrict__ adj,
                                                 const float* __restrict__ a_s,
                                                 const float* __restrict__ a_d,
                                                 float* __restrict__ ebuf,
                                                 float* __restrict__ ssum){
  int k = blockIdx.x*256 + threadIdx.x;
  if(k >= ETOT) return;
  int s, d;
  if(k < EE){ s = adj[k]; d = adj[EE + k]; } else { s = k - EE; d = s; }
  #pragma unroll
  for(int h = 0; h < 6; h++){
    float v = a_s[s*6 + h] + a_d[d*6 + h];
    v = v > 0.f ? v : 0.2f * v;              // leaky_relu(0.2)
    float w = __expf(v);
    ebuf[(size_t)k*6 + h] = w;
    atomicAdd(ssum + d*6 + h, w);
  }
}

// ---------- CSR aggregation (bf16 gather): y[n,:] = relu( sum_e alpha*hx[src] + bias ), bf16 out ----------
__global__ __launch_bounds__(384) void aggregate(const ushort_t* __restrict__ hx,
                                                 const float* __restrict__ wbuf,
                                                 const float* __restrict__ ssum,
                                                 const int* __restrict__ row_start,
                                                 const int* __restrict__ csr_src,
                                                 const int* __restrict__ csr_eid,
                                                 const float* __restrict__ bias,
                                                 ushort_t* __restrict__ y){
  int n = blockIdx.x, t = threadIdx.x, h = t >> 6;   // thread t owns channels 2t,2t+1
  int e0 = row_start[n], e1 = row_start[n+1];
  float a0 = 0.f, a1 = 0.f;
  for(int i = e0; i < e1; i++){
    int s = csr_src[i];
    int k = csr_eid[i];
    float w = wbuf[(size_t)k*6 + h];                 // wave-uniform
    uint_t u = ((const uint_t*)(hx + (size_t)s*FF))[t];
    a0 = fmaf(w, bf_lo(u), a0);
    a1 = fmaf(w, bf_hi(u), a1);
  }
  float inv = 1.f/ssum[n*6 + h];
  float2 bv = ((const float2*)bias)[t];
  float v0 = a0*inv + bv.x;
  float v1 = a1*inv + bv.y;
  v0 = v0 > 0.f ? v0 : 0.f;
  v1 = v1 > 0.f ? v1 : 0.f;
  uint_t p = (uint_t)f2bf(v0) | ((uint_t)f2bf(v1) << 16);
  ((uint_t*)(y + (size_t)n*FF))[t] = p;
}

// ---------- batch-norm stats (bf16 input) ----------
__global__ __launch_bounds__(384) void bn_stats(const ushort_t* __restrict__ y,
                                                float* __restrict__ sums,
                                                float* __restrict__ sumsq){
  int t = threadIdx.x;
  float s0=0.f,s1=0.f,q0=0.f,q1=0.f;
  for(int n = blockIdx.x; n < NN; n += gridDim.x){
    uint_t u = ((const uint_t*)(y + (size_t)n*FF))[t];
    float lo = bf_lo(u), hi = bf_hi(u);
    s0 += lo; q0 += lo*lo;
    s1 += hi; q1 += hi*hi;
  }
  atomicAdd(sums + 2*t,     s0); atomicAdd(sumsq + 2*t,     q0);
  atomicAdd(sums + 2*t + 1, s1); atomicAdd(sumsq + 2*t + 1, q1);
}

__global__ __launch_bounds__(256) void bn_final(const float* __restrict__ sums,
                                                const float* __restrict__ sumsq,
                                                const float* __restrict__ g,
                                                const float* __restrict__ be,
                                                float* __restrict__ scale,
                                                float* __restrict__ shift){
  int f = blockIdx.x*256 + threadIdx.x;
  if(f >= FF) return;
  float mu  = sums[f] * (1.f/NN);
  float var = sumsq[f] * (1.f/NN) - mu*mu;
  float sc = g[f] * rsqrtf(var + BN_EPS);
  scale[f] = sc;
  shift[f] = be[f] - mu*sc;
}

// ---------- final segment max pool ----------
__global__ __launch_bounds__(256) void init_out(unsigned* __restrict__ outEnc){
  int i = blockIdx.x*256 + threadIdx.x;
  if(i < BB*CC) outEnc[i] = FENC_NEG_INF;
}
#define SEG_ROWS 40
__global__ __launch_bounds__(128) void segmax(const float* __restrict__ z,
                                              const int* __restrict__ ibatch,
                                              unsigned* __restrict__ outEnc){
  int c = threadIdx.x;
  int r0 = blockIdx.x*SEG_ROWS;
  int r1 = r0 + SEG_ROWS; if(r1 > NN) r1 = NN;
  if(r0 >= NN) return;
  int g = ibatch[r0];
  float m = -__builtin_inff();
  for(int r = r0; r < r1; r++){
    int gr = ibatch[r];
    if(gr != g){ atomicMax(outEnc + g*CC + c, fenc(m)); g = gr; m = -__builtin_inff(); }
    float v = z[(size_t)r*CC + c];
    m = fmaxf(m, v);
  }
  atomicMax(outEnc + g*CC + c, fenc(m));
}
__global__ __launch_bounds__(256) void decode_out(const unsigned* __restrict__ outEnc,
                                                  float* __restrict__ out){
  int i = blockIdx.x*256 + threadIdx.x;
  if(i < BB*CC) out[i] = fdec(outEnc[i]);
}

extern "C" void kernel_launch(void* const* d_in, const int* in_sizes, int n_in,
                              void* d_out, int out_size, void* d_ws, size_t ws_size,
                              hipStream_t stream){
  const float* feat  = (const float*)d_in[0];
  const int*   adj   = (const int*)d_in[1];
  const int*   ibatch= (const int*)d_in[2];
  const float* W1    = (const float*)d_in[3];
  const float* atts1 = (const float*)d_in[4];
  const float* attd1 = (const float*)d_in[5];
  const float* b1    = (const float*)d_in[6];
  const float* g1    = (const float*)d_in[7];
  const float* be1   = (const float*)d_in[8];
  const float* W2    = (const float*)d_in[9];
  const float* atts2 = (const float*)d_in[10];
  const float* attd2 = (const float*)d_in[11];
  const float* b2    = (const float*)d_in[12];
  const float* g2    = (const float*)d_in[13];
  const float* be2   = (const float*)d_in[14];
  const float* linW  = (const float*)d_in[15];
  const float* linb  = (const float*)d_in[16];
  float* out = (float*)d_out;

  size_t off = 0;
  auto alloc = [&](size_t bytes) -> void* {
    void* p = (char*)d_ws + off;
    off += (bytes + 255) & ~(size_t)255;
    return p;
  };
  ushort_t* hx      = (ushort_t*)alloc((size_t)NN*FF*2);   // bf16 pre-aggregation features
  ushort_t* yB      = (ushort_t*)alloc((size_t)MP*FF*2);   // bf16 post-aggregation activations
  ushort_t* featB   = (ushort_t*)alloc((size_t)MP*INC*2);
  float*    z       = (float*)alloc((size_t)NN*CC*4);
  ushort_t* W1t     = (ushort_t*)alloc((size_t)FF*INC*2);
  ushort_t* W2t     = (ushort_t*)alloc((size_t)FF*FF*2);
  ushort_t* linWt   = (ushort_t*)alloc((size_t)CC*FF*2);
  float*    bias2p  = (float*)alloc((size_t)FF*4);
  float*    biasLp  = (float*)alloc((size_t)CC*4);
  float*    a_s     = (float*)alloc((size_t)NN*6*4);
  float*    a_d     = (float*)alloc((size_t)NN*6*4);
  float*    ebuf    = (float*)alloc((size_t)ETOT*6*4);
  float*    ssum    = (float*)alloc((size_t)NN*6*4);
  int*      deg     = (int*)alloc((size_t)NN*4);
  int*      row_start=(int*)alloc((size_t)(NN+1)*4);
  int*      pos     = (int*)alloc((size_t)NN*4);
  int*      csr_src = (int*)alloc((size_t)ETOT*4);
  int*      csr_eid = (int*)alloc((size_t)ETOT*4);
  float*    sums    = (float*)alloc((size_t)2*FF*4);
  float*    sumsq   = sums + FF;
  float*    scale   = (float*)alloc((size_t)FF*4);
  float*    shift   = (float*)alloc((size_t)FF*4);
  unsigned* outEnc  = (unsigned*)alloc((size_t)BB*CC*4);

  const int EB = (ETOT + 255)/256;

  // CSR build
  hipMemsetAsync(deg, 0, NN*4, stream);
  count_deg<<<EB,256,0,stream>>>(adj, deg);
  scan_deg<<<1,1024,0,stream>>>(deg, row_start, pos);
  scatter_edges<<<EB,256,0,stream>>>(adj, pos, csr_src, csr_eid);

  // weight transpose (unscaled) + feat convert
  transpose_bf<<<dim3(FF/32, INC/32),256,0,stream>>>(W1, W1t, INC, FF, nullptr);
  conv_bf16<<<(NN*INC/4+255)/256,256,0,stream>>>(feat, featB, NN*INC/4);

  // ---- conv1 ----
  gemm_bt<<<dim3(FF/128, MP/128),256,0,stream>>>(featB, W1t, nullptr, hx, NN, FF, INC, nullptr);
  att_dots<<<NN,384,0,stream>>>(hx, atts1, attd1, a_s, a_d);
  hipMemsetAsync(ssum, 0, NN*6*4, stream);
  edge_soft<<<EB,256,0,stream>>>(adj, a_s, a_d, ebuf, ssum);
  aggregate<<<NN,384,0,stream>>>(hx, ebuf, ssum, row_start, csr_src, csr_eid, b1, yB);
  hipMemsetAsync(sums, 0, 2*FF*4, stream);
  bn_stats<<<256,384,0,stream>>>(yB, sums, sumsq);
  bn_final<<<3,256,0,stream>>>(sums, sumsq, g1, be1, scale, shift);

  // ---- conv2 (BN1 folded into W2 scale + bias) ----
  transpose_bf<<<dim3(FF/32, FF/32),256,0,stream>>>(W2, W2t, FF, FF, scale);
  bias_fold<<<3,256,0,stream>>>(W2, shift, nullptr, bias2p, FF, FF);
  gemm_bt<<<dim3(FF/128, MP/128),256,0,stream>>>(yB, W2t, nullptr, hx, NN, FF, FF, bias2p);
  att_dots<<<NN,384,0,stream>>>(hx, atts2, attd2, a_s, a_d);
  hipMemsetAsync(ssum, 0, NN*6*4, stream);
  edge_soft<<<EB,256,0,stream>>>(adj, a_s, a_d, ebuf, ssum);
  aggregate<<<NN,384,0,stream>>>(hx, ebuf, ssum, row_start, csr_src, csr_eid, b2, yB);
  hipMemsetAsync(sums, 0, 2*FF*4, stream);
  bn_stats<<<256,384,0,stream>>>(yB, sums, sumsq);
  bn_final<<<3,256,0,stream>>>(sums, sumsq, g2, be2, scale, shift);

  // ---- linear head (BN2 folded into linW scale + bias) + global max pool ----
  transpose_bf<<<dim3(CC/32, FF/32),256,0,stream>>>(linW, linWt, FF, CC, scale);
  bias_fold<<<1,256,0,stream>>>(linW, shift, linb, biasLp, FF, CC);
  gemm_bt<<<dim3(CC/128, MP/128),256,0,stream>>>(yB, linWt, z, nullptr, NN, CC, FF, biasLp);
  init_out<<<(BB*CC+255)/256,256,0,stream>>>(outEnc);
  segmax<<<(NN+SEG_ROWS-1)/SEG_ROWS,128,0,stream>>>(z, ibatch, outEnc);
  decode_out<<<(BB*CC+255)/256,256,0,stream>>>(outEnc, out);
}

// Round 4
// 520.692 us; speedup vs baseline: 1.6101x; 1.6101x over previous
//
#include <hip/hip_runtime.h>

#define NN 10000
#define MP 10112      // 79*128, padded row count for MFMA GEMM A-tiles
#define EE 100000
#define ETOT 110000   // EE + NN self loops
#define INC 256
#define HH 6
#define CC 128
#define FF 768        // HH*CC
#define BB 64
#define BN_EPS 1e-5f

typedef unsigned short ushort_t;
typedef unsigned int uint_t;
typedef __attribute__((ext_vector_type(8))) short bf16x8;
typedef __attribute__((ext_vector_type(4))) float f32x4;
#define AS1 __attribute__((address_space(1)))
#define AS3 __attribute__((address_space(3)))

// ---------- float <-> order-preserving uint encoding (for atomicMax on float) ----------
__device__ __forceinline__ unsigned fenc(float v){
  unsigned u = __float_as_uint(v);
  return (u & 0x80000000u) ? ~u : (u | 0x80000000u);
}
__device__ __forceinline__ float fdec(unsigned u){
  return (u & 0x80000000u) ? __uint_as_float(u & 0x7FFFFFFFu) : __uint_as_float(~u);
}
#define FENC_NEG_INF 0x007FFFFFu   // fenc(-inf)

__device__ __forceinline__ ushort_t f2bf(float v){   // RNE fp32 -> bf16
  unsigned u = __float_as_uint(v);
  u += 0x7FFFu + ((u >> 16) & 1u);
  return (ushort_t)(u >> 16);
}
__device__ __forceinline__ float bf_lo(uint_t u){ return __uint_as_float(u << 16); }
__device__ __forceinline__ float bf_hi(uint_t u){ return __uint_as_float(u & 0xFFFF0000u); }

// ---------- CSR build ----------
__global__ __launch_bounds__(256) void count_deg(const int* __restrict__ adj, int* __restrict__ deg){
  int k = blockIdx.x*256 + threadIdx.x;
  if(k >= ETOT) return;
  int d = (k < EE) ? adj[EE + k] : (k - EE);
  atomicAdd(deg + d, 1);
}

__global__ __launch_bounds__(1024) void scan_deg(const int* __restrict__ deg,
                                                 int* __restrict__ row_start,
                                                 int* __restrict__ pos){
  __shared__ int wsum[16];
  __shared__ int wexcl[16];
  __shared__ int carry, ctot;
  int t = threadIdx.x, wave = t >> 6, lane = t & 63;
  if(t == 0) carry = 0;
  __syncthreads();
  for(int base = 0; base < NN; base += 1024){
    int i = base + t;
    int v = (i < NN) ? deg[i] : 0;
    int s = v;
    #pragma unroll
    for(int off = 1; off < 64; off <<= 1){ int x = __shfl_up(s, off); if(lane >= off) s += x; }
    if(lane == 63) wsum[wave] = s;
    __syncthreads();
    if(t < 16){
      int ws = wsum[t], sc = ws;
      #pragma unroll
      for(int off = 1; off < 16; off <<= 1){ int x = __shfl_up(sc, off); if(t >= off) sc += x; }
      wexcl[t] = sc - ws;
      if(t == 15) ctot = sc;
    }
    __syncthreads();
    int c = carry;
    if(i < NN){ int excl = c + wexcl[wave] + s - v; row_start[i] = excl; pos[i] = excl; }
    __syncthreads();
    if(t == 0) carry = c + ctot;
  }
  __syncthreads();
  if(t == 0) row_start[NN] = carry;
}

__global__ __launch_bounds__(256) void scatter_edges(const int* __restrict__ adj,
                                                     int* __restrict__ pos,
                                                     int* __restrict__ csr_src,
                                                     int* __restrict__ csr_eid){
  int k = blockIdx.x*256 + threadIdx.x;
  if(k >= ETOT) return;
  int s, d;
  if(k < EE){ s = adj[k]; d = adj[EE + k]; } else { s = k - EE; d = s; }
  int i = atomicAdd(pos + d, 1);
  csr_src[i] = s;
  csr_eid[i] = k;
}

// ---------- fp32 -> bf16 convert ----------
__global__ __launch_bounds__(256) void conv_bf16(const float* __restrict__ in,
                                                 ushort_t* __restrict__ out, int n4){
  int i = blockIdx.x*256 + threadIdx.x;
  if(i >= n4) return;
  float4 v = ((const float4*)in)[i];
  ushort4 o;
  o.x = f2bf(v.x); o.y = f2bf(v.y); o.z = f2bf(v.z); o.w = f2bf(v.w);
  ((ushort4*)out)[i] = o;
}

// ---------- W[K,N] fp32 -> Wt[N,K] bf16, optional per-k scale (BN fold) ----------
__global__ __launch_bounds__(256) void transpose_bf(const float* __restrict__ in,
                                                    ushort_t* __restrict__ out,
                                                    int K, int N,
                                                    const float* __restrict__ sc){
  __shared__ ushort_t tile[32][33];
  int kb = blockIdx.y*32, nb = blockIdx.x*32;
  int tx = threadIdx.x & 31, ty = threadIdx.x >> 5;
  #pragma unroll
  for(int r = ty; r < 32; r += 8){
    float v = in[(size_t)(kb + r)*N + nb + tx];
    if(sc) v *= sc[kb + r];
    tile[tx][r] = f2bf(v);
  }
  __syncthreads();
  #pragma unroll
  for(int r = ty; r < 32; r += 8)
    out[(size_t)(nb + r)*K + kb + tx] = tile[r][tx];
}

// ---------- bias fold: out[o] += sum_{k in chunk} shift[k]*W[k,o]  (+base on chunk 0) ----------
// K-parallel grid (blockIdx.y = k-chunk) + atomicAdd; out must be zeroed first.
#define BF_KCHUNK 64
__global__ __launch_bounds__(256) void bias_fold(const float* __restrict__ W,
                                                 const float* __restrict__ shift,
                                                 const float* __restrict__ base,
                                                 float* __restrict__ out, int K, int N){
  int o = blockIdx.x*256 + threadIdx.x;
  if(o >= N) return;
  int k0 = blockIdx.y*BF_KCHUNK;
  int k1 = k0 + BF_KCHUNK; if(k1 > K) k1 = K;
  float s = 0.f;
  for(int k = k0; k < k1; k++) s = fmaf(shift[k], W[(size_t)k*N + o], s);
  if(k0 == 0 && base) s += base[o];
  atomicAdd(out + o, s);
}

// ---------- bf16 MFMA GEMM: C[M,N] = A[MP,K] * Bt[N,K]^T (+bias), out fp32 or bf16 ----------
__global__ __launch_bounds__(256) void gemm_bt(const ushort_t* __restrict__ A,
                                               const ushort_t* __restrict__ Bt,
                                               float* __restrict__ Cf,
                                               ushort_t* __restrict__ Cb,
                                               int M, int N, int K,
                                               const float* __restrict__ bias){
  __shared__ ushort_t As[128*32];
  __shared__ ushort_t Bs[128*32];
  int tid = threadIdx.x;
  int bm = blockIdx.y*128, bn = blockIdx.x*128;
  int w = tid >> 6, lane = tid & 63;
  int wr = (w >> 1)*64, wc = (w & 1)*64;
  int quad = lane >> 4, l15 = lane & 15;

  f32x4 acc[4][4];
  #pragma unroll
  for(int i=0;i<4;i++)
    #pragma unroll
    for(int j=0;j<4;j++) acc[i][j] = (f32x4){0.f,0.f,0.f,0.f};

  int ch0 = tid, ch1 = tid + 256;
  int ar0 = ch0 >> 2, ac0 = (ch0 & 3) << 3;
  int ar1 = ch1 >> 2, ac1 = (ch1 & 3) << 3;
  const ushort_t* Ag0 = A + (size_t)(bm + ar0)*K + ac0;
  const ushort_t* Ag1 = A + (size_t)(bm + ar1)*K + ac1;
  const ushort_t* Bg0 = Bt + (size_t)(bn + ar0)*K + ac0;
  const ushort_t* Bg1 = Bt + (size_t)(bn + ar1)*K + ac1;

  for(int k0 = 0; k0 < K; k0 += 32){
    __builtin_amdgcn_global_load_lds((const AS1 uint_t*)(Ag0 + k0),
                                     (AS3 uint_t*)(As + ch0*8), 16, 0, 0);
    __builtin_amdgcn_global_load_lds((const AS1 uint_t*)(Ag1 + k0),
                                     (AS3 uint_t*)(As + ch1*8), 16, 0, 0);
    __builtin_amdgcn_global_load_lds((const AS1 uint_t*)(Bg0 + k0),
                                     (AS3 uint_t*)(Bs + ch0*8), 16, 0, 0);
    __builtin_amdgcn_global_load_lds((const AS1 uint_t*)(Bg1 + k0),
                                     (AS3 uint_t*)(Bs + ch1*8), 16, 0, 0);
    __syncthreads();

    bf16x8 a[4], b[4];
    #pragma unroll
    for(int i=0;i<4;i++) a[i] = *(const bf16x8*)&As[(wr + i*16 + l15)*32 + quad*8];
    #pragma unroll
    for(int j=0;j<4;j++) b[j] = *(const bf16x8*)&Bs[(wc + j*16 + l15)*32 + quad*8];
    #pragma unroll
    for(int i=0;i<4;i++)
      #pragma unroll
      for(int j=0;j<4;j++)
        acc[i][j] = __builtin_amdgcn_mfma_f32_16x16x32_bf16(a[i], b[j], acc[i][j], 0, 0, 0);
    __syncthreads();
  }

  // epilogue: C/D layout col=lane&15, row=quad*4+reg
  #pragma unroll
  for(int j=0;j<4;j++){
    int gc = bn + wc + j*16 + l15;
    float bv = bias ? bias[gc] : 0.f;
    #pragma unroll
    for(int i=0;i<4;i++){
      #pragma unroll
      for(int r=0;r<4;r++){
        int gr = bm + wr + i*16 + quad*4 + r;
        if(gr < M){
          float val = acc[i][j][r] + bv;
          if(Cb) Cb[(size_t)gr*N + gc] = f2bf(val);
          else   Cf[(size_t)gr*N + gc] = val;
        }
      }
    }
  }
}

// ---------- per-node attention dots (bf16 hx): thread t owns channels 2t,2t+1; wave w = head ----------
__global__ __launch_bounds__(384) void att_dots(const ushort_t* __restrict__ hx,
                                                const float* __restrict__ atts,
                                                const float* __restrict__ attd,
                                                float* __restrict__ a_s,
                                                float* __restrict__ a_d){
  int n = blockIdx.x, t = threadIdx.x, wave = t >> 6, lane = t & 63;
  uint_t u = ((const uint_t*)(hx + (size_t)n*FF))[t];
  float lo = bf_lo(u), hi = bf_hi(u);
  float2 as = ((const float2*)atts)[t];
  float2 ad = ((const float2*)attd)[t];
  float s = lo*as.x + hi*as.y;
  float d = lo*ad.x + hi*ad.y;
  #pragma unroll
  for(int off = 1; off < 64; off <<= 1){ s += __shfl_xor(s, off); d += __shfl_xor(d, off); }
  if(lane == 0){ a_s[n*6 + wave] = s; a_d[n*6 + wave] = d; }
}

// ---------- edge softmax weights (no max-subtraction; logits are O(1) by construction) ----------
__global__ __launch_bounds__(256) void edge_soft(const int* __restrict__ adj,
                                                 const float* __restrict__ a_s,
                                                 const float* __restrict__ a_d,
                                                 float* __restrict__ ebuf,
                                                 float* __restrict__ ssum){
  int k = blockIdx.x*256 + threadIdx.x;
  if(k >= ETOT) return;
  int s, d;
  if(k < EE){ s = adj[k]; d = adj[EE + k]; } else { s = k - EE; d = s; }
  #pragma unroll
  for(int h = 0; h < 6; h++){
    float v = a_s[s*6 + h] + a_d[d*6 + h];
    v = v > 0.f ? v : 0.2f * v;              // leaky_relu(0.2)
    float w = __expf(v);
    ebuf[(size_t)k*6 + h] = w;
    atomicAdd(ssum + d*6 + h, w);
  }
}

// ---------- CSR aggregation (bf16 gather): y[n,:] = relu( sum_e alpha*hx[src] + bias ), bf16 out ----------
__global__ __launch_bounds__(384) void aggregate(const ushort_t* __restrict__ hx,
                                                 const float* __restrict__ wbuf,
                                                 const float* __restrict__ ssum,
                                                 const int* __restrict__ row_start,
                                                 const int* __restrict__ csr_src,
                                                 const int* __restrict__ csr_eid,
                                                 const float* __restrict__ bias,
                                                 ushort_t* __restrict__ y){
  int n = blockIdx.x, t = threadIdx.x, h = t >> 6;   // thread t owns channels 2t,2t+1
  int e0 = row_start[n], e1 = row_start[n+1];
  float a0 = 0.f, a1 = 0.f;
  for(int i = e0; i < e1; i++){
    int s = csr_src[i];
    int k = csr_eid[i];
    float w = wbuf[(size_t)k*6 + h];                 // wave-uniform
    uint_t u = ((const uint_t*)(hx + (size_t)s*FF))[t];
    a0 = fmaf(w, bf_lo(u), a0);
    a1 = fmaf(w, bf_hi(u), a1);
  }
  float inv = 1.f/ssum[n*6 + h];
  float2 bv = ((const float2*)bias)[t];
  float v0 = a0*inv + bv.x;
  float v1 = a1*inv + bv.y;
  v0 = v0 > 0.f ? v0 : 0.f;
  v1 = v1 > 0.f ? v1 : 0.f;
  uint_t p = (uint_t)f2bf(v0) | ((uint_t)f2bf(v1) << 16);
  ((uint_t*)(y + (size_t)n*FF))[t] = p;
}

// ---------- batch-norm stats (bf16 input) ----------
__global__ __launch_bounds__(384) void bn_stats(const ushort_t* __restrict__ y,
                                                float* __restrict__ sums,
                                                float* __restrict__ sumsq){
  int t = threadIdx.x;
  float s0=0.f,s1=0.f,q0=0.f,q1=0.f;
  for(int n = blockIdx.x; n < NN; n += gridDim.x){
    uint_t u = ((const uint_t*)(y + (size_t)n*FF))[t];
    float lo = bf_lo(u), hi = bf_hi(u);
    s0 += lo; q0 += lo*lo;
    s1 += hi; q1 += hi*hi;
  }
  atomicAdd(sums + 2*t,     s0); atomicAdd(sumsq + 2*t,     q0);
  atomicAdd(sums + 2*t + 1, s1); atomicAdd(sumsq + 2*t + 1, q1);
}

__global__ __launch_bounds__(256) void bn_final(const float* __restrict__ sums,
                                                const float* __restrict__ sumsq,
                                                const float* __restrict__ g,
                                                const float* __restrict__ be,
                                                float* __restrict__ scale,
                                                float* __restrict__ shift){
  int f = blockIdx.x*256 + threadIdx.x;
  if(f >= FF) return;
  float mu  = sums[f] * (1.f/NN);
  float var = sumsq[f] * (1.f/NN) - mu*mu;
  float sc = g[f] * rsqrtf(var + BN_EPS);
  scale[f] = sc;
  shift[f] = be[f] - mu*sc;
}

// ---------- final segment max pool ----------
__global__ __launch_bounds__(256) void init_out(unsigned* __restrict__ outEnc){
  int i = blockIdx.x*256 + threadIdx.x;
  if(i < BB*CC) outEnc[i] = FENC_NEG_INF;
}
#define SEG_ROWS 40
__global__ __launch_bounds__(128) void segmax(const float* __restrict__ z,
                                              const int* __restrict__ ibatch,
                                              unsigned* __restrict__ outEnc){
  int c = threadIdx.x;
  int r0 = blockIdx.x*SEG_ROWS;
  int r1 = r0 + SEG_ROWS; if(r1 > NN) r1 = NN;
  if(r0 >= NN) return;
  int g = ibatch[r0];
  float m = -__builtin_inff();
  for(int r = r0; r < r1; r++){
    int gr = ibatch[r];
    if(gr != g){ atomicMax(outEnc + g*CC + c, fenc(m)); g = gr; m = -__builtin_inff(); }
    float v = z[(size_t)r*CC + c];
    m = fmaxf(m, v);
  }
  atomicMax(outEnc + g*CC + c, fenc(m));
}
__global__ __launch_bounds__(256) void decode_out(const unsigned* __restrict__ outEnc,
                                                  float* __restrict__ out){
  int i = blockIdx.x*256 + threadIdx.x;
  if(i < BB*CC) out[i] = fdec(outEnc[i]);
}

extern "C" void kernel_launch(void* const* d_in, const int* in_sizes, int n_in,
                              void* d_out, int out_size, void* d_ws, size_t ws_size,
                              hipStream_t stream){
  const float* feat  = (const float*)d_in[0];
  const int*   adj   = (const int*)d_in[1];
  const int*   ibatch= (const int*)d_in[2];
  const float* W1    = (const float*)d_in[3];
  const float* atts1 = (const float*)d_in[4];
  const float* attd1 = (const float*)d_in[5];
  const float* b1    = (const float*)d_in[6];
  const float* g1    = (const float*)d_in[7];
  const float* be1   = (const float*)d_in[8];
  const float* W2    = (const float*)d_in[9];
  const float* atts2 = (const float*)d_in[10];
  const float* attd2 = (const float*)d_in[11];
  const float* b2    = (const float*)d_in[12];
  const float* g2    = (const float*)d_in[13];
  const float* be2   = (const float*)d_in[14];
  const float* linW  = (const float*)d_in[15];
  const float* linb  = (const float*)d_in[16];
  float* out = (float*)d_out;

  size_t off = 0;
  auto alloc = [&](size_t bytes) -> void* {
    void* p = (char*)d_ws + off;
    off += (bytes + 255) & ~(size_t)255;
    return p;
  };
  ushort_t* hx      = (ushort_t*)alloc((size_t)NN*FF*2);   // bf16 pre-aggregation features
  ushort_t* yB      = (ushort_t*)alloc((size_t)MP*FF*2);   // bf16 post-aggregation activations
  ushort_t* featB   = (ushort_t*)alloc((size_t)MP*INC*2);
  float*    z       = (float*)alloc((size_t)NN*CC*4);
  ushort_t* W1t     = (ushort_t*)alloc((size_t)FF*INC*2);
  ushort_t* W2t     = (ushort_t*)alloc((size_t)FF*FF*2);
  ushort_t* linWt   = (ushort_t*)alloc((size_t)CC*FF*2);
  float*    bias2p  = (float*)alloc((size_t)FF*4);
  float*    biasLp  = (float*)alloc((size_t)CC*4);
  float*    a_s     = (float*)alloc((size_t)NN*6*4);
  float*    a_d     = (float*)alloc((size_t)NN*6*4);
  float*    ebuf    = (float*)alloc((size_t)ETOT*6*4);
  float*    ssum    = (float*)alloc((size_t)NN*6*4);
  int*      deg     = (int*)alloc((size_t)NN*4);
  int*      row_start=(int*)alloc((size_t)(NN+1)*4);
  int*      pos     = (int*)alloc((size_t)NN*4);
  int*      csr_src = (int*)alloc((size_t)ETOT*4);
  int*      csr_eid = (int*)alloc((size_t)ETOT*4);
  float*    sums    = (float*)alloc((size_t)2*FF*4);
  float*    sumsq   = sums + FF;
  float*    scale   = (float*)alloc((size_t)FF*4);
  float*    shift   = (float*)alloc((size_t)FF*4);
  unsigned* outEnc  = (unsigned*)alloc((size_t)BB*CC*4);

  const int EB = (ETOT + 255)/256;

  // CSR build
  hipMemsetAsync(deg, 0, NN*4, stream);
  count_deg<<<EB,256,0,stream>>>(adj, deg);
  scan_deg<<<1,1024,0,stream>>>(deg, row_start, pos);
  scatter_edges<<<EB,256,0,stream>>>(adj, pos, csr_src, csr_eid);

  // weight transpose (unscaled) + feat convert
  transpose_bf<<<dim3(FF/32, INC/32),256,0,stream>>>(W1, W1t, INC, FF, nullptr);
  conv_bf16<<<(NN*INC/4+255)/256,256,0,stream>>>(feat, featB, NN*INC/4);

  // ---- conv1 ----
  gemm_bt<<<dim3(FF/128, MP/128),256,0,stream>>>(featB, W1t, nullptr, hx, NN, FF, INC, nullptr);
  att_dots<<<NN,384,0,stream>>>(hx, atts1, attd1, a_s, a_d);
  hipMemsetAsync(ssum, 0, NN*6*4, stream);
  edge_soft<<<EB,256,0,stream>>>(adj, a_s, a_d, ebuf, ssum);
  aggregate<<<NN,384,0,stream>>>(hx, ebuf, ssum, row_start, csr_src, csr_eid, b1, yB);
  hipMemsetAsync(sums, 0, 2*FF*4, stream);
  bn_stats<<<256,384,0,stream>>>(yB, sums, sumsq);
  bn_final<<<3,256,0,stream>>>(sums, sumsq, g1, be1, scale, shift);

  // ---- conv2 (BN1 folded into W2 scale + bias) ----
  transpose_bf<<<dim3(FF/32, FF/32),256,0,stream>>>(W2, W2t, FF, FF, scale);
  hipMemsetAsync(bias2p, 0, FF*4, stream);
  bias_fold<<<dim3(3, FF/BF_KCHUNK),256,0,stream>>>(W2, shift, nullptr, bias2p, FF, FF);
  gemm_bt<<<dim3(FF/128, MP/128),256,0,stream>>>(yB, W2t, nullptr, hx, NN, FF, FF, bias2p);
  att_dots<<<NN,384,0,stream>>>(hx, atts2, attd2, a_s, a_d);
  hipMemsetAsync(ssum, 0, NN*6*4, stream);
  edge_soft<<<EB,256,0,stream>>>(adj, a_s, a_d, ebuf, ssum);
  aggregate<<<NN,384,0,stream>>>(hx, ebuf, ssum, row_start, csr_src, csr_eid, b2, yB);
  hipMemsetAsync(sums, 0, 2*FF*4, stream);
  bn_stats<<<256,384,0,stream>>>(yB, sums, sumsq);
  bn_final<<<3,256,0,stream>>>(sums, sumsq, g2, be2, scale, shift);

  // ---- linear head (BN2 folded into linW scale + bias) + global max pool ----
  transpose_bf<<<dim3(CC/32, FF/32),256,0,stream>>>(linW, linWt, FF, CC, scale);
  hipMemsetAsync(biasLp, 0, CC*4, stream);
  bias_fold<<<dim3(1, FF/BF_KCHUNK),256,0,stream>>>(linW, shift, linb, biasLp, FF, CC);
  gemm_bt<<<dim3(CC/128, MP/128),256,0,stream>>>(yB, linWt, z, nullptr, NN, CC, FF, biasLp);
  init_out<<<(BB*CC+255)/256,256,0,stream>>>(outEnc);
  segmax<<<(NN+SEG_ROWS-1)/SEG_ROWS,128,0,stream>>>(z, ibatch, outEnc);
  decode_out<<<(BB*CC+255)/256,256,0,stream>>>(outEnc, out);
}

// Round 5
// 391.583 us; speedup vs baseline: 2.1410x; 1.3297x over previous
//
#include <hip/hip_runtime.h>

#define NN 10000
#define MP 10112      // 79*128, padded row count for MFMA GEMM A-tiles
#define EE 100000
#define ETOT 110000   // EE + NN self loops
#define INC 256
#define HH 6
#define CC 128
#define FF 768        // HH*CC
#define BB 64
#define BN_EPS 1e-5f

typedef unsigned short ushort_t;
typedef unsigned int uint_t;
typedef __attribute__((ext_vector_type(8))) short bf16x8;
typedef __attribute__((ext_vector_type(4))) float f32x4;
#define AS1 __attribute__((address_space(1)))
#define AS3 __attribute__((address_space(3)))

// ---------- float <-> order-preserving uint encoding (for atomicMax on float) ----------
__device__ __forceinline__ unsigned fenc(float v){
  unsigned u = __float_as_uint(v);
  return (u & 0x80000000u) ? ~u : (u | 0x80000000u);
}
__device__ __forceinline__ float fdec(unsigned u){
  return (u & 0x80000000u) ? __uint_as_float(u & 0x7FFFFFFFu) : __uint_as_float(~u);
}
#define FENC_NEG_INF 0x007FFFFFu   // fenc(-inf)

__device__ __forceinline__ ushort_t f2bf(float v){   // RNE fp32 -> bf16
  unsigned u = __float_as_uint(v);
  u += 0x7FFFu + ((u >> 16) & 1u);
  return (ushort_t)(u >> 16);
}
__device__ __forceinline__ float bf_lo(uint_t u){ return __uint_as_float(u << 16); }
__device__ __forceinline__ float bf_hi(uint_t u){ return __uint_as_float(u & 0xFFFF0000u); }

// ---------- CSR build ----------
__global__ __launch_bounds__(256) void count_deg(const int* __restrict__ adj, int* __restrict__ deg){
  int k = blockIdx.x*256 + threadIdx.x;
  if(k >= ETOT) return;
  int d = (k < EE) ? adj[EE + k] : (k - EE);
  atomicAdd(deg + d, 1);
}

__global__ __launch_bounds__(1024) void scan_deg(const int* __restrict__ deg,
                                                 int* __restrict__ row_start,
                                                 int* __restrict__ pos){
  __shared__ int wsum[16];
  __shared__ int wexcl[16];
  __shared__ int carry, ctot;
  int t = threadIdx.x, wave = t >> 6, lane = t & 63;
  if(t == 0) carry = 0;
  __syncthreads();
  for(int base = 0; base < NN; base += 1024){
    int i = base + t;
    int v = (i < NN) ? deg[i] : 0;
    int s = v;
    #pragma unroll
    for(int off = 1; off < 64; off <<= 1){ int x = __shfl_up(s, off); if(lane >= off) s += x; }
    if(lane == 63) wsum[wave] = s;
    __syncthreads();
    if(t < 16){
      int ws = wsum[t], sc = ws;
      #pragma unroll
      for(int off = 1; off < 16; off <<= 1){ int x = __shfl_up(sc, off); if(t >= off) sc += x; }
      wexcl[t] = sc - ws;
      if(t == 15) ctot = sc;
    }
    __syncthreads();
    int c = carry;
    if(i < NN){ int excl = c + wexcl[wave] + s - v; row_start[i] = excl; pos[i] = excl; }
    __syncthreads();
    if(t == 0) carry = c + ctot;
  }
  __syncthreads();
  if(t == 0) row_start[NN] = carry;
}

__global__ __launch_bounds__(256) void scatter_edges(const int* __restrict__ adj,
                                                     int* __restrict__ pos,
                                                     int* __restrict__ csr_src,
                                                     int* __restrict__ csr_pos){
  int k = blockIdx.x*256 + threadIdx.x;
  if(k >= ETOT) return;
  int s, d;
  if(k < EE){ s = adj[k]; d = adj[EE + k]; } else { s = k - EE; d = s; }
  int i = atomicAdd(pos + d, 1);
  csr_src[i] = s;
  csr_pos[k] = i;
}

// ---------- fp32 -> bf16 convert ----------
__global__ __launch_bounds__(256) void conv_bf16(const float* __restrict__ in,
                                                 ushort_t* __restrict__ out, int n4){
  int i = blockIdx.x*256 + threadIdx.x;
  if(i >= n4) return;
  float4 v = ((const float4*)in)[i];
  ushort4 o;
  o.x = f2bf(v.x); o.y = f2bf(v.y); o.z = f2bf(v.z); o.w = f2bf(v.w);
  ((ushort4*)out)[i] = o;
}

// ---------- W[K,N] fp32 -> Wt[N,K] bf16, optional per-k scale (BN fold) ----------
__global__ __launch_bounds__(256) void transpose_bf(const float* __restrict__ in,
                                                    ushort_t* __restrict__ out,
                                                    int K, int N,
                                                    const float* __restrict__ sc){
  __shared__ ushort_t tile[32][33];
  int kb = blockIdx.y*32, nb = blockIdx.x*32;
  int tx = threadIdx.x & 31, ty = threadIdx.x >> 5;
  #pragma unroll
  for(int r = ty; r < 32; r += 8){
    float v = in[(size_t)(kb + r)*N + nb + tx];
    if(sc) v *= sc[kb + r];
    tile[tx][r] = f2bf(v);
  }
  __syncthreads();
  #pragma unroll
  for(int r = ty; r < 32; r += 8)
    out[(size_t)(nb + r)*K + kb + tx] = tile[r][tx];
}

// ---------- bias fold: out[o] += sum_{k in chunk} shift[k]*W[k,o]  (+base on chunk 0) ----------
#define BF_KCHUNK 64
__global__ __launch_bounds__(256) void bias_fold(const float* __restrict__ W,
                                                 const float* __restrict__ shift,
                                                 const float* __restrict__ base,
                                                 float* __restrict__ out, int K, int N){
  int o = blockIdx.x*256 + threadIdx.x;
  if(o >= N) return;
  int k0 = blockIdx.y*BF_KCHUNK;
  int k1 = k0 + BF_KCHUNK; if(k1 > K) k1 = K;
  float s = 0.f;
  for(int k = k0; k < k1; k++) s = fmaf(shift[k], W[(size_t)k*N + o], s);
  if(k0 == 0 && base) s += base[o];
  atomicAdd(out + o, s);
}

// ---------- bf16 MFMA GEMM + fused attention head-dots ----------
// C[M,N] = A[MP,K] * Bt[N,K]^T (+bias); when atts!=null, block cols = one head
// (N=768, 128-col tiles) and the epilogue also emits a_s[n,h], a_d[n,h].
__global__ __launch_bounds__(256) void gemm_bt(const ushort_t* __restrict__ A,
                                               const ushort_t* __restrict__ Bt,
                                               float* __restrict__ Cf,
                                               ushort_t* __restrict__ Cb,
                                               int M, int N, int K,
                                               const float* __restrict__ bias,
                                               const float* __restrict__ atts,
                                               const float* __restrict__ attd,
                                               float* __restrict__ a_s,
                                               float* __restrict__ a_d){
  __shared__ ushort_t As[128*32];
  __shared__ ushort_t Bs[128*32];
  __shared__ float sred[128], dred[128];
  int tid = threadIdx.x;
  int bm = blockIdx.y*128, bn = blockIdx.x*128;
  int w = tid >> 6, lane = tid & 63;
  int wr = (w >> 1)*64, wc = (w & 1)*64;
  int quad = lane >> 4, l15 = lane & 15;

  f32x4 acc[4][4];
  #pragma unroll
  for(int i=0;i<4;i++)
    #pragma unroll
    for(int j=0;j<4;j++) acc[i][j] = (f32x4){0.f,0.f,0.f,0.f};

  int ch0 = tid, ch1 = tid + 256;
  int ar0 = ch0 >> 2, ac0 = (ch0 & 3) << 3;
  int ar1 = ch1 >> 2, ac1 = (ch1 & 3) << 3;
  const ushort_t* Ag0 = A + (size_t)(bm + ar0)*K + ac0;
  const ushort_t* Ag1 = A + (size_t)(bm + ar1)*K + ac1;
  const ushort_t* Bg0 = Bt + (size_t)(bn + ar0)*K + ac0;
  const ushort_t* Bg1 = Bt + (size_t)(bn + ar1)*K + ac1;

  for(int k0 = 0; k0 < K; k0 += 32){
    __builtin_amdgcn_global_load_lds((const AS1 uint_t*)(Ag0 + k0),
                                     (AS3 uint_t*)(As + ch0*8), 16, 0, 0);
    __builtin_amdgcn_global_load_lds((const AS1 uint_t*)(Ag1 + k0),
                                     (AS3 uint_t*)(As + ch1*8), 16, 0, 0);
    __builtin_amdgcn_global_load_lds((const AS1 uint_t*)(Bg0 + k0),
                                     (AS3 uint_t*)(Bs + ch0*8), 16, 0, 0);
    __builtin_amdgcn_global_load_lds((const AS1 uint_t*)(Bg1 + k0),
                                     (AS3 uint_t*)(Bs + ch1*8), 16, 0, 0);
    __syncthreads();

    bf16x8 a[4], b[4];
    #pragma unroll
    for(int i=0;i<4;i++) a[i] = *(const bf16x8*)&As[(wr + i*16 + l15)*32 + quad*8];
    #pragma unroll
    for(int j=0;j<4;j++) b[j] = *(const bf16x8*)&Bs[(wc + j*16 + l15)*32 + quad*8];
    #pragma unroll
    for(int i=0;i<4;i++)
      #pragma unroll
      for(int j=0;j<4;j++)
        acc[i][j] = __builtin_amdgcn_mfma_f32_16x16x32_bf16(a[i], b[j], acc[i][j], 0, 0, 0);
    __syncthreads();
  }

  // epilogue: C/D layout col=lane&15, row=quad*4+reg
  int h = bn >> 7;
  float bv4[4], as4[4] = {0,0,0,0}, ad4[4] = {0,0,0,0};
  #pragma unroll
  for(int j=0;j<4;j++){
    int gc = bn + wc + j*16 + l15;
    bv4[j] = bias ? bias[gc] : 0.f;
  }
  if(atts){
    #pragma unroll
    for(int j=0;j<4;j++){
      int lc = wc + j*16 + l15;
      as4[j] = atts[h*CC + lc];
      ad4[j] = attd[h*CC + lc];
    }
    if(tid < 128){ sred[tid] = 0.f; dred[tid] = 0.f; }
    __syncthreads();
  }
  #pragma unroll
  for(int i=0;i<4;i++){
    #pragma unroll
    for(int r=0;r<4;r++){
      int rl = wr + i*16 + quad*4 + r;
      int gr = bm + rl;
      float sp = 0.f, dp = 0.f;
      #pragma unroll
      for(int j=0;j<4;j++){
        float val = acc[i][j][r] + bv4[j];
        if(gr < M){
          int gc = bn + wc + j*16 + l15;
          if(Cb) Cb[(size_t)gr*N + gc] = f2bf(val);
          else   Cf[(size_t)gr*N + gc] = val;
        }
        sp = fmaf(val, as4[j], sp);
        dp = fmaf(val, ad4[j], dp);
      }
      if(atts){
        #pragma unroll
        for(int off = 1; off < 16; off <<= 1){
          sp += __shfl_xor(sp, off);
          dp += __shfl_xor(dp, off);
        }
        if(l15 == 0){ atomicAdd(&sred[rl], sp); atomicAdd(&dred[rl], dp); }
      }
    }
  }
  if(atts){
    __syncthreads();
    if(tid < 128){
      int gr = bm + tid;
      if(gr < M){ a_s[gr*6 + h] = sred[tid]; a_d[gr*6 + h] = dred[tid]; }
    }
  }
}

// ---------- edge softmax weights, one thread per (edge, head); CSR-ordered output ----------
__global__ __launch_bounds__(256) void edge_soft(const int* __restrict__ adj,
                                                 const int* __restrict__ csr_pos,
                                                 const float* __restrict__ a_s,
                                                 const float* __restrict__ a_d,
                                                 float* __restrict__ ebuf,
                                                 float* __restrict__ ssum){
  int idx = blockIdx.x*256 + threadIdx.x;   // = k*6 + h
  if(idx >= ETOT*6) return;
  int k = idx / 6, h = idx - k*6;
  int s, d;
  if(k < EE){ s = adj[k]; d = adj[EE + k]; } else { s = k - EE; d = s; }
  float v = a_s[s*6 + h] + a_d[d*6 + h];
  v = v > 0.f ? v : 0.2f * v;               // leaky_relu(0.2)
  float w = __expf(v);
  ebuf[(size_t)csr_pos[k]*6 + h] = w;
  atomicAdd(ssum + d*6 + h, w);
}

// ---------- CSR aggregation (bf16 gather, chunk-8 ILP): y[n,:] = relu(sum alpha*hx[src]+bias) ----------
__global__ __launch_bounds__(384) void aggregate(const ushort_t* __restrict__ hx,
                                                 const float* __restrict__ ebuf,   // CSR-ordered
                                                 const float* __restrict__ ssum,
                                                 const int* __restrict__ row_start,
                                                 const int* __restrict__ csr_src,
                                                 const float* __restrict__ bias,
                                                 ushort_t* __restrict__ y){
  int n = blockIdx.x, t = threadIdx.x, h = t >> 6;   // thread t owns channels 2t,2t+1
  int e0 = row_start[n], e1 = row_start[n+1];
  float a0 = 0.f, a1 = 0.f;
  int i = e0;
  for(; i + 8 <= e1; i += 8){
    int s[8]; float wv[8]; uint_t u[8];
    #pragma unroll
    for(int q=0;q<8;q++) s[q] = csr_src[i+q];
    #pragma unroll
    for(int q=0;q<8;q++) wv[q] = ebuf[(size_t)(i+q)*6 + h];
    #pragma unroll
    for(int q=0;q<8;q++) u[q] = ((const uint_t*)(hx + (size_t)s[q]*FF))[t];
    #pragma unroll
    for(int q=0;q<8;q++){ a0 = fmaf(wv[q], bf_lo(u[q]), a0); a1 = fmaf(wv[q], bf_hi(u[q]), a1); }
  }
  if(i + 4 <= e1){
    int s[4]; float wv[4]; uint_t u[4];
    #pragma unroll
    for(int q=0;q<4;q++) s[q] = csr_src[i+q];
    #pragma unroll
    for(int q=0;q<4;q++) wv[q] = ebuf[(size_t)(i+q)*6 + h];
    #pragma unroll
    for(int q=0;q<4;q++) u[q] = ((const uint_t*)(hx + (size_t)s[q]*FF))[t];
    #pragma unroll
    for(int q=0;q<4;q++){ a0 = fmaf(wv[q], bf_lo(u[q]), a0); a1 = fmaf(wv[q], bf_hi(u[q]), a1); }
    i += 4;
  }
  for(; i < e1; i++){
    int s = csr_src[i];
    float wv = ebuf[(size_t)i*6 + h];
    uint_t u = ((const uint_t*)(hx + (size_t)s*FF))[t];
    a0 = fmaf(wv, bf_lo(u), a0); a1 = fmaf(wv, bf_hi(u), a1);
  }
  float inv = 1.f/ssum[n*6 + h];
  float2 bv = ((const float2*)bias)[t];
  float v0 = a0*inv + bv.x;
  float v1 = a1*inv + bv.y;
  v0 = v0 > 0.f ? v0 : 0.f;
  v1 = v1 > 0.f ? v1 : 0.f;
  uint_t p = (uint_t)f2bf(v0) | ((uint_t)f2bf(v1) << 16);
  ((uint_t*)(y + (size_t)n*FF))[t] = p;
}

// ---------- batch-norm stats (bf16 input) ----------
__global__ __launch_bounds__(384) void bn_stats(const ushort_t* __restrict__ y,
                                                float* __restrict__ sums,
                                                float* __restrict__ sumsq){
  int t = threadIdx.x;
  float s0=0.f,s1=0.f,q0=0.f,q1=0.f;
  for(int n = blockIdx.x; n < NN; n += gridDim.x){
    uint_t u = ((const uint_t*)(y + (size_t)n*FF))[t];
    float lo = bf_lo(u), hi = bf_hi(u);
    s0 += lo; q0 += lo*lo;
    s1 += hi; q1 += hi*hi;
  }
  atomicAdd(sums + 2*t,     s0); atomicAdd(sumsq + 2*t,     q0);
  atomicAdd(sums + 2*t + 1, s1); atomicAdd(sumsq + 2*t + 1, q1);
}

__global__ __launch_bounds__(256) void bn_final(const float* __restrict__ sums,
                                                const float* __restrict__ sumsq,
                                                const float* __restrict__ g,
                                                const float* __restrict__ be,
                                                float* __restrict__ scale,
                                                float* __restrict__ shift){
  int f = blockIdx.x*256 + threadIdx.x;
  if(f >= FF) return;
  float mu  = sums[f] * (1.f/NN);
  float var = sumsq[f] * (1.f/NN) - mu*mu;
  float sc = g[f] * rsqrtf(var + BN_EPS);
  scale[f] = sc;
  shift[f] = be[f] - mu*sc;
}

// ---------- final segment max pool ----------
__global__ __launch_bounds__(256) void init_out(unsigned* __restrict__ outEnc){
  int i = blockIdx.x*256 + threadIdx.x;
  if(i < BB*CC) outEnc[i] = FENC_NEG_INF;
}
#define SEG_ROWS 40
__global__ __launch_bounds__(128) void segmax(const float* __restrict__ z,
                                              const int* __restrict__ ibatch,
                                              unsigned* __restrict__ outEnc){
  int c = threadIdx.x;
  int r0 = blockIdx.x*SEG_ROWS;
  int r1 = r0 + SEG_ROWS; if(r1 > NN) r1 = NN;
  if(r0 >= NN) return;
  int g = ibatch[r0];
  float m = -__builtin_inff();
  for(int r = r0; r < r1; r++){
    int gr = ibatch[r];
    if(gr != g){ atomicMax(outEnc + g*CC + c, fenc(m)); g = gr; m = -__builtin_inff(); }
    float v = z[(size_t)r*CC + c];
    m = fmaxf(m, v);
  }
  atomicMax(outEnc + g*CC + c, fenc(m));
}
__global__ __launch_bounds__(256) void decode_out(const unsigned* __restrict__ outEnc,
                                                  float* __restrict__ out){
  int i = blockIdx.x*256 + threadIdx.x;
  if(i < BB*CC) out[i] = fdec(outEnc[i]);
}

extern "C" void kernel_launch(void* const* d_in, const int* in_sizes, int n_in,
                              void* d_out, int out_size, void* d_ws, size_t ws_size,
                              hipStream_t stream){
  const float* feat  = (const float*)d_in[0];
  const int*   adj   = (const int*)d_in[1];
  const int*   ibatch= (const int*)d_in[2];
  const float* W1    = (const float*)d_in[3];
  const float* atts1 = (const float*)d_in[4];
  const float* attd1 = (const float*)d_in[5];
  const float* b1    = (const float*)d_in[6];
  const float* g1    = (const float*)d_in[7];
  const float* be1   = (const float*)d_in[8];
  const float* W2    = (const float*)d_in[9];
  const float* atts2 = (const float*)d_in[10];
  const float* attd2 = (const float*)d_in[11];
  const float* b2    = (const float*)d_in[12];
  const float* g2    = (const float*)d_in[13];
  const float* be2   = (const float*)d_in[14];
  const float* linW  = (const float*)d_in[15];
  const float* linb  = (const float*)d_in[16];
  float* out = (float*)d_out;

  size_t off = 0;
  auto alloc = [&](size_t bytes) -> void* {
    void* p = (char*)d_ws + off;
    off += (bytes + 255) & ~(size_t)255;
    return p;
  };
  ushort_t* hx      = (ushort_t*)alloc((size_t)NN*FF*2);   // bf16 pre-aggregation features
  ushort_t* yB      = (ushort_t*)alloc((size_t)MP*FF*2);   // bf16 post-aggregation activations
  ushort_t* featB   = (ushort_t*)alloc((size_t)MP*INC*2);
  float*    z       = (float*)alloc((size_t)NN*CC*4);
  ushort_t* W1t     = (ushort_t*)alloc((size_t)FF*INC*2);
  ushort_t* W2t     = (ushort_t*)alloc((size_t)FF*FF*2);
  ushort_t* linWt   = (ushort_t*)alloc((size_t)CC*FF*2);
  float*    bias2p  = (float*)alloc((size_t)FF*4);
  float*    biasLp  = (float*)alloc((size_t)CC*4);
  float*    a_s     = (float*)alloc((size_t)NN*6*4);
  float*    a_d     = (float*)alloc((size_t)NN*6*4);
  float*    ebuf    = (float*)alloc((size_t)ETOT*6*4);
  float*    ssum    = (float*)alloc((size_t)NN*6*4);
  int*      deg     = (int*)alloc((size_t)NN*4);
  int*      row_start=(int*)alloc((size_t)(NN+1)*4);
  int*      pos     = (int*)alloc((size_t)NN*4);
  int*      csr_src = (int*)alloc((size_t)ETOT*4);
  int*      csr_pos = (int*)alloc((size_t)ETOT*4);
  float*    sums    = (float*)alloc((size_t)2*FF*4);
  float*    sumsq   = sums + FF;
  float*    scale   = (float*)alloc((size_t)FF*4);
  float*    shift   = (float*)alloc((size_t)FF*4);
  unsigned* outEnc  = (unsigned*)alloc((size_t)BB*CC*4);

  const int EB = (ETOT + 255)/256;
  const int EB6 = (ETOT*6 + 255)/256;

  // CSR build
  hipMemsetAsync(deg, 0, NN*4, stream);
  count_deg<<<EB,256,0,stream>>>(adj, deg);
  scan_deg<<<1,1024,0,stream>>>(deg, row_start, pos);
  scatter_edges<<<EB,256,0,stream>>>(adj, pos, csr_src, csr_pos);

  // weight transpose (unscaled) + feat convert
  transpose_bf<<<dim3(FF/32, INC/32),256,0,stream>>>(W1, W1t, INC, FF, nullptr);
  conv_bf16<<<(NN*INC/4+255)/256,256,0,stream>>>(feat, featB, NN*INC/4);

  // ---- conv1 (dots fused into GEMM epilogue) ----
  gemm_bt<<<dim3(FF/128, MP/128),256,0,stream>>>(featB, W1t, nullptr, hx, NN, FF, INC,
                                                 nullptr, atts1, attd1, a_s, a_d);
  hipMemsetAsync(ssum, 0, NN*6*4, stream);
  edge_soft<<<EB6,256,0,stream>>>(adj, csr_pos, a_s, a_d, ebuf, ssum);
  aggregate<<<NN,384,0,stream>>>(hx, ebuf, ssum, row_start, csr_src, b1, yB);
  hipMemsetAsync(sums, 0, 2*FF*4, stream);
  bn_stats<<<256,384,0,stream>>>(yB, sums, sumsq);
  bn_final<<<3,256,0,stream>>>(sums, sumsq, g1, be1, scale, shift);

  // ---- conv2 (BN1 folded into W2 scale + bias; dots fused) ----
  transpose_bf<<<dim3(FF/32, FF/32),256,0,stream>>>(W2, W2t, FF, FF, scale);
  hipMemsetAsync(bias2p, 0, FF*4, stream);
  bias_fold<<<dim3(3, FF/BF_KCHUNK),256,0,stream>>>(W2, shift, nullptr, bias2p, FF, FF);
  gemm_bt<<<dim3(FF/128, MP/128),256,0,stream>>>(yB, W2t, nullptr, hx, NN, FF, FF,
                                                 bias2p, atts2, attd2, a_s, a_d);
  hipMemsetAsync(ssum, 0, NN*6*4, stream);
  edge_soft<<<EB6,256,0,stream>>>(adj, csr_pos, a_s, a_d, ebuf, ssum);
  aggregate<<<NN,384,0,stream>>>(hx, ebuf, ssum, row_start, csr_src, b2, yB);
  hipMemsetAsync(sums, 0, 2*FF*4, stream);
  bn_stats<<<256,384,0,stream>>>(yB, sums, sumsq);
  bn_final<<<3,256,0,stream>>>(sums, sumsq, g2, be2, scale, shift);

  // ---- linear head (BN2 folded into linW scale + bias) + global max pool ----
  transpose_bf<<<dim3(CC/32, FF/32),256,0,stream>>>(linW, linWt, FF, CC, scale);
  hipMemsetAsync(biasLp, 0, CC*4, stream);
  bias_fold<<<dim3(1, FF/BF_KCHUNK),256,0,stream>>>(linW, shift, linb, biasLp, FF, CC);
  gemm_bt<<<dim3(CC/128, MP/128),256,0,stream>>>(yB, linWt, z, nullptr, NN, CC, FF,
                                                 biasLp, nullptr, nullptr, nullptr, nullptr);
  init_out<<<(BB*CC+255)/256,256,0,stream>>>(outEnc);
  segmax<<<(NN+SEG_ROWS-1)/SEG_ROWS,128,0,stream>>>(z, ibatch, outEnc);
  decode_out<<<(BB*CC+255)/256,256,0,stream>>>(outEnc, out);
}